// Round 7
// baseline (1283.930 us; speedup 1.0000x reference)
//
#include <hip/hip_runtime.h>
#include <math.h>

#define BB 16
#define NN 4096

__device__ __forceinline__ float sq3(float dx, float dy, float dz) {
    // match numpy: ((dx*dx + dy*dy) + dz*dz), no fma contraction
    return __fadd_rn(__fadd_rn(__fmul_rn(dx, dx), __fmul_rn(dy, dy)), __fmul_rn(dz, dz));
}

// Candidate carried through the wave argmax: packed key + the point's coords.
// P = (float_bits(dist) << 32) | ~idx  (dist >= 0 -> monotone bits; ~idx gives
// first-index tie-break under u64 max = jnp.argmax semantics). P > 0 always,
// so 0 (the update_dpp "old" value for disabled/invalid lanes) never wins and
// the stale coords of a losing lane are never selected.
struct FCand { unsigned long long P; float x, y, z; };

template<int CTRL, int RMASK>
__device__ __forceinline__ FCand dpp_cand_step(FCand c) {
    int lo = __builtin_amdgcn_update_dpp(0, (int)(unsigned)c.P,         CTRL, RMASK, 0xf, true);
    int hi = __builtin_amdgcn_update_dpp(0, (int)(unsigned)(c.P >> 32), CTRL, RMASK, 0xf, true);
    int ox = __builtin_amdgcn_update_dpp(0, __float_as_int(c.x),        CTRL, RMASK, 0xf, true);
    int oy = __builtin_amdgcn_update_dpp(0, __float_as_int(c.y),        CTRL, RMASK, 0xf, true);
    int oz = __builtin_amdgcn_update_dpp(0, __float_as_int(c.z),        CTRL, RMASK, 0xf, true);
    unsigned long long oP = ((unsigned long long)(unsigned)hi << 32) | (unsigned)lo;
    if (oP > c.P) { c.P = oP; c.x = __int_as_float(ox); c.y = __int_as_float(oy); c.z = __int_as_float(oz); }
    return c;
}

__device__ __forceinline__ FCand dpp_wave_max_cand(FCand c) {
    c = dpp_cand_step<0x111, 0xf>(c);   // row_shr:1
    c = dpp_cand_step<0x112, 0xf>(c);   // row_shr:2
    c = dpp_cand_step<0x114, 0xf>(c);   // row_shr:4
    c = dpp_cand_step<0x118, 0xf>(c);   // row_shr:8
    c = dpp_cand_step<0x142, 0xa>(c);   // row_bcast15
    c = dpp_cand_step<0x143, 0xc>(c);   // row_bcast31 -> lane 63 has wave max
    return c;
}

// ---------------- FPS (one block per batch, sequential argmax) ----------------
// All point coords live in registers (px/py/pz/dist), no LDS staging arrays.
// The winner's coords ride through the DPP reduce and the cross-wave slot, so
// there is NO dependent sx[far] LDS read after the barrier (r6 critical path).
// No global ops in the serial loop; thread (it % TPB) latches the entering-far
// coords and everything is written once at the end.
template<int NPTS, int NPOINT, int TPB>
__global__ __launch_bounds__(TPB) void fps_kernel(const float* __restrict__ xyz,   // [B][NPTS][3]
                                                  float* __restrict__ newxyz,      // [B][NPOINT][3]
                                                  float* __restrict__ out_t,       // optional transposed rows 0..2, stride ts
                                                  int ts) {
    constexpr int PPT = NPTS / TPB;
    constexpr int NW  = TPB / 64;
    constexpr int LAT = (NPOINT + TPB - 1) / TPB;
    __shared__ unsigned long long slotP[2][NW];
    __shared__ float4 slotC[2][NW];
    const int b = blockIdx.x;
    const int tid = threadIdx.x;
    const float* base = xyz + (size_t)b * NPTS * 3;
    float px[PPT], py[PPT], pz[PPT], dist[PPT];
#pragma unroll
    for (int k = 0; k < PPT; k++) {
        int p = tid + k * TPB;
        px[k] = base[p * 3 + 0];
        py[k] = base[p * 3 + 1];
        pz[k] = base[p * 3 + 2];
        dist[k] = 1e10f;
    }
    float fx = base[0], fy = base[1], fz = base[2];   // far = point 0 initially
    float mx[LAT], my[LAT], mz[LAT];
#pragma unroll
    for (int l = 0; l < LAT; l++) { mx[l] = 0.f; my[l] = 0.f; mz[l] = 0.f; }
    const int lane = tid & 63, wid = tid >> 6;
    for (int it = 0; it < NPOINT; it++) {
#pragma unroll
        for (int l = 0; l < LAT; l++)
            if (tid + l * TPB == it) { mx[l] = fx; my[l] = fy; mz[l] = fz; }
        float bv = -1.0f; int bi = 0;
        float cx = 0.f, cy = 0.f, cz = 0.f;
#pragma unroll
        for (int k = 0; k < PPT; k++) {
            float d = sq3(px[k] - fx, py[k] - fy, pz[k] - fz);
            float nd = fminf(dist[k], d);
            dist[k] = nd;
            if (nd > bv) { bv = nd; bi = tid + k * TPB; cx = px[k]; cy = py[k]; cz = pz[k]; }
        }
        FCand c;
        c.P = ((unsigned long long)__float_as_uint(bv) << 32)
            | (unsigned long long)(~(unsigned)bi & 0xFFFFFFFFull);
        c.x = cx; c.y = cy; c.z = cz;
        c = dpp_wave_max_cand(c);
        int bufi = it & 1;
        if (lane == 63) {
            slotP[bufi][wid] = c.P;
            slotC[bufi][wid] = make_float4(c.x, c.y, c.z, 0.f);
        }
        __syncthreads();
        unsigned long long bP = slotP[bufi][0];
        float4 bC = slotC[bufi][0];
#pragma unroll
        for (int w = 1; w < NW; w++) {
            unsigned long long v = slotP[bufi][w];
            float4 vc = slotC[bufi][w];
            if (v > bP) { bP = v; bC = vc; }
        }
        fx = bC.x; fy = bC.y; fz = bC.z;
    }
#pragma unroll
    for (int l = 0; l < LAT; l++) {
        int o = tid + l * TPB;
        if (o < NPOINT) {
            newxyz[((size_t)b * NPOINT + o) * 3 + 0] = mx[l];
            newxyz[((size_t)b * NPOINT + o) * 3 + 1] = my[l];
            newxyz[((size_t)b * NPOINT + o) * 3 + 2] = mz[l];
            if (out_t) {
                out_t[0 * ts + b * NPOINT + o] = mx[l];
                out_t[1 * ts + b * NPOINT + o] = my[l];
                out_t[2 * ts + b * NPOINT + o] = mz[l];
            }
        }
    }
}

// ---------------- ball query: one wave per center, ballot rounds ----------------
template<int NS>
__global__ __launch_bounds__(256) void ballquery_kernel(const float* __restrict__ pts, int n,
                                                        const float* __restrict__ centers, int S,
                                                        float r2, int* __restrict__ outidx) {
    int gid  = blockIdx.x * blockDim.x + threadIdx.x;
    int wave = gid >> 6, lane = gid & 63;
    int b = wave / S, s = wave % S;
    const float* c = centers + ((size_t)b * S + s) * 3;
    float cx = c[0], cy = c[1], cz = c[2];
    const float* pb = pts + (size_t)b * n * 3;
    int* out = outidx + ((size_t)b * S + s) * NS;
    int total = 0, first = -1;
    int rounds = n >> 6;
    for (int r = 0; r < rounds; r++) {
        int p = (r << 6) + lane;
        float dx = pb[p * 3 + 0] - cx, dy = pb[p * 3 + 1] - cy, dz = pb[p * 3 + 2] - cz;
        float d = sq3(dx, dy, dz);
        bool pred = (d <= r2);
        unsigned long long mask = __ballot(pred);
        if (first < 0 && mask) first = (r << 6) + (__ffsll(mask) - 1);
        if (pred) {
            int rank = total + __popcll(mask & ((1ull << lane) - 1ull));
            if (rank < NS) out[rank] = p;
        }
        total += __popcll(mask);
        if (total >= NS) break;
    }
    for (int j = total + lane; j < NS; j += 64) out[j] = first;
}

// ---------------- SA1 MLP: 3->64->64->128, max over 32 nbrs. 1 wave = 2 centers ----------------
__global__ __launch_bounds__(64, 2) void sa1_kernel(const float* __restrict__ xyz, const float* __restrict__ l1x,
                                                 const int* __restrict__ idx1,
                                                 const float* __restrict__ W1, const float* __restrict__ B1,
                                                 const float* __restrict__ W2, const float* __restrict__ B2,
                                                 const float* __restrict__ W3, const float* __restrict__ B3,
                                                 float* __restrict__ l1f) {
    __shared__ float ht[64 * 64];
    int lane = threadIdx.x;
    int b = blockIdx.x >> 8;
    int s = ((blockIdx.x & 255) << 1) | (lane >> 5);
    int nn = lane & 31;
    int center = b * 512 + s;
    int ii = idx1[center * 32 + nn];
    float px = xyz[((size_t)b * NN + ii) * 3 + 0] - l1x[(size_t)center * 3 + 0];
    float py = xyz[((size_t)b * NN + ii) * 3 + 1] - l1x[(size_t)center * 3 + 1];
    float pz = xyz[((size_t)b * NN + ii) * 3 + 2] - l1x[(size_t)center * 3 + 2];
#pragma unroll
    for (int c = 0; c < 64; c++)
        ht[c * 64 + lane] = fmaxf(B1[c] + px * W1[c] + py * W1[64 + c] + pz * W1[128 + c], 0.0f);
    __syncthreads();
    float h2[64];
#pragma unroll
    for (int c = 0; c < 64; c++) h2[c] = B2[c];
    for (int k = 0; k < 64; k++) {
        float xk = ht[k * 64 + lane];
        const float* wr = W2 + k * 64;
#pragma unroll
        for (int c = 0; c < 64; c++) h2[c] += xk * wr[c];
    }
    __syncthreads();
#pragma unroll
    for (int c = 0; c < 64; c++) ht[c * 64 + lane] = fmaxf(h2[c], 0.0f);
    __syncthreads();
#pragma unroll
    for (int half = 0; half < 2; half++) {
        float o[64];
#pragma unroll
        for (int j = 0; j < 64; j++) o[j] = B3[half * 64 + j];
        for (int k = 0; k < 64; k++) {
            float xk = ht[k * 64 + lane];
            const float* wr = W3 + k * 128 + half * 64;
#pragma unroll
            for (int j = 0; j < 64; j++) o[j] += xk * wr[j];
        }
#pragma unroll
        for (int j = 0; j < 64; j++) {
            float v = fmaxf(o[j], 0.0f);
#pragma unroll
            for (int m = 16; m >= 1; m >>= 1) v = fmaxf(v, __shfl_xor(v, m));
            o[j] = v;
        }
        if (nn == 0) {
#pragma unroll
            for (int j = 0; j < 64; j++) l1f[(size_t)center * 128 + half * 64 + j] = o[j];
        }
    }
}

// ---------------- SA2 MLP: 131->128->128->256, max over 64 nbrs ----------------
// 256 threads = 4 waves x 32 channels (r5 fix: occupancy/s_load pipelining).
__global__ __launch_bounds__(256, 2) void sa2_kernel(const float* __restrict__ l1x, const float* __restrict__ l2x,
                                                  const float* __restrict__ l1f, const int* __restrict__ idx2,
                                                  const float* __restrict__ W1, const float* __restrict__ B1,
                                                  const float* __restrict__ W2, const float* __restrict__ B2,
                                                  const float* __restrict__ W3, const float* __restrict__ B3,
                                                  float* __restrict__ x3t) {
    __shared__ float ht[128 * 64];
    int tid = threadIdx.x;
    int w = __builtin_amdgcn_readfirstlane(tid >> 6);   // 0..3, wave-uniform -> SGPR
    int lane = tid & 63;
    int b = blockIdx.x >> 7, s = blockIdx.x & 127;
    int center = b * 128 + s;
    int ii = idx2[center * 64 + lane];
    float cx = l2x[(size_t)center * 3 + 0], cy = l2x[(size_t)center * 3 + 1], cz = l2x[(size_t)center * 3 + 2];
    const float* pr = l1x + ((size_t)b * 512 + ii) * 3;
    float px = pr[0] - cx, py = pr[1] - cy, pz = pr[2] - cz;
    const float4* frow = (const float4*)(l1f + ((size_t)b * 512 + ii) * 128);
    float h[32];
#pragma unroll
    for (int j = 0; j < 32; j++) {
        int c = w * 32 + j;
        h[j] = B1[c] + px * W1[c] + py * W1[128 + c] + pz * W1[256 + c];
    }
    for (int k4 = 0; k4 < 32; k4++) {
        float4 f = frow[k4];
        const float* wr = W1 + (3 + k4 * 4) * 128 + w * 32;
#pragma unroll
        for (int j = 0; j < 32; j++)
            h[j] += f.x * wr[j] + f.y * wr[128 + j] + f.z * wr[256 + j] + f.w * wr[384 + j];
    }
#pragma unroll
    for (int j = 0; j < 32; j++) ht[(w * 32 + j) * 64 + lane] = fmaxf(h[j], 0.0f);
    __syncthreads();
    float h2[32];
#pragma unroll
    for (int j = 0; j < 32; j++) h2[j] = B2[w * 32 + j];
    for (int k = 0; k < 128; k++) {
        float xk = ht[k * 64 + lane];
        const float* wr = W2 + k * 128 + w * 32;
#pragma unroll
        for (int j = 0; j < 32; j++) h2[j] += xk * wr[j];
    }
    __syncthreads();
#pragma unroll
    for (int j = 0; j < 32; j++) ht[(w * 32 + j) * 64 + lane] = fmaxf(h2[j], 0.0f);
    __syncthreads();
#pragma unroll
    for (int half = 0; half < 2; half++) {
        float o[32];
#pragma unroll
        for (int j = 0; j < 32; j++) o[j] = B3[w * 64 + half * 32 + j];
        for (int k = 0; k < 128; k++) {
            float xk = ht[k * 64 + lane];
            const float* wr = W3 + k * 256 + w * 64 + half * 32;
#pragma unroll
            for (int j = 0; j < 32; j++) o[j] += xk * wr[j];
        }
#pragma unroll
        for (int j = 0; j < 32; j++) {
            float v = fmaxf(o[j], 0.0f);
#pragma unroll
            for (int m = 32; m >= 1; m >>= 1) v = fmaxf(v, __shfl_xor(v, m));
            o[j] = v;
        }
        if (lane == 0) {
#pragma unroll
            for (int j = 0; j < 32; j++)
                x3t[(size_t)(3 + w * 64 + half * 32 + j) * 2048 + center] = o[j];
        }
    }
}

// ---------------- transposed GEMM for SA3: in_t[K][2048] -> out_t[COUT][2048] (relu), opt. seg-max ----------------
__global__ void zerog_kernel(float* __restrict__ g) { g[blockIdx.x * 1024 + threadIdx.x] = 0.0f; }

template<int K, int COUT, int CPT, bool MAXOUT>
__global__ __launch_bounds__(64, 4) void gemm_t_kernel(const float* __restrict__ in_t,
                                                    const float* __restrict__ W,
                                                    const float* __restrict__ bias,
                                                    float* __restrict__ outp) {
    int lane = threadIdx.x;
    int rw = blockIdx.x & 31, cg = blockIdx.x >> 5;
    int row = rw * 64 + lane;
    int cbase = cg * CPT;
    float acc[CPT];
#pragma unroll
    for (int j = 0; j < CPT; j++) acc[j] = bias[cbase + j];
    for (int k = 0; k < K; k++) {
        float xk = in_t[(size_t)k * 2048 + row];
        const float* wr = W + (size_t)k * COUT + cbase;
#pragma unroll
        for (int j = 0; j < CPT; j++) acc[j] += xk * wr[j];
    }
    if (MAXOUT) {
        int b = row >> 7;
#pragma unroll
        for (int j = 0; j < CPT; j++) {
            float v = fmaxf(acc[j], 0.0f);
#pragma unroll
            for (int m = 32; m >= 1; m >>= 1) v = fmaxf(v, __shfl_xor(v, m));
            if (lane == 0)
                atomicMax((int*)(outp + (size_t)b * 1024 + cbase + j), __float_as_int(v));
        }
    } else {
#pragma unroll
        for (int j = 0; j < CPT; j++)
            outp[(size_t)(cbase + j) * 2048 + row] = fmaxf(acc[j], 0.0f);
    }
}

// ---------------- FC heads ----------------
__global__ __launch_bounds__(512) void head_kernel(const float* __restrict__ g,
                                                   const float* __restrict__ lw1, const float* __restrict__ lb1,
                                                   const float* __restrict__ lw2, const float* __restrict__ lb2,
                                                   const float* __restrict__ fw1, const float* __restrict__ fb1,
                                                   const float* __restrict__ fw2, const float* __restrict__ fb2,
                                                   const float* __restrict__ pm, const float* __restrict__ ps,
                                                   const float* __restrict__ rm, const float* __restrict__ rs,
                                                   float* __restrict__ out) {
    __shared__ float gl[1024], a1[256], f1[512];
    int b = blockIdx.x, t = threadIdx.x;
    for (int i = t; i < 1024; i += 512) gl[i] = g[b * 1024 + i];
    __syncthreads();
    {
        float acc = fb1[t];
        for (int k = 0; k < 1024; k++) acc += gl[k] * fw1[k * 512 + t];
        f1[t] = fmaxf(acc, 0.0f);
    }
    if (t < 256) {
        float acc = lb1[t];
        for (int k = 0; k < 1024; k++) acc += gl[k] * lw1[k * 256 + t];
        a1[t] = fmaxf(acc, 0.0f);
    }
    __syncthreads();
    if (t < 2) {
        float z = lb2[t];
        for (int k = 0; k < 256; k++) z += a1[k] * lw2[k * 2 + t];
        out[b * 20 + t] = 1.0f / (1.0f + expf(-z));
    } else if (t < 20) {
        int i = t - 2;
        float z = fb2[i];
        for (int k = 0; k < 512; k++) z += f1[k] * fw2[k * 18 + i];
        float sc, mn;
        if (i < 3)       { sc = ps[i];      mn = pm[i]; }
        else if (i < 9)  { sc = rs[i - 3];  mn = rm[i - 3]; }
        else if (i < 12) { sc = ps[i - 9];  mn = pm[i - 9]; }
        else             { sc = rs[i - 12]; mn = rm[i - 12]; }
        out[b * 20 + t] = z * sc + mn;
    }
}

static inline size_t align256(size_t x) { return (x + 255) & ~(size_t)255; }

extern "C" void kernel_launch(void* const* d_in, const int* in_sizes, int n_in,
                              void* d_out, int out_size, void* d_ws, size_t ws_size,
                              hipStream_t stream) {
    const float* points = (const float*)d_in[0];
    const float* w10 = (const float*)d_in[1];  const float* b10 = (const float*)d_in[2];
    const float* w11 = (const float*)d_in[3];  const float* b11 = (const float*)d_in[4];
    const float* w12 = (const float*)d_in[5];  const float* b12 = (const float*)d_in[6];
    const float* w20 = (const float*)d_in[7];  const float* b20 = (const float*)d_in[8];
    const float* w21 = (const float*)d_in[9];  const float* b21 = (const float*)d_in[10];
    const float* w22 = (const float*)d_in[11]; const float* b22 = (const float*)d_in[12];
    const float* w30 = (const float*)d_in[13]; const float* b30 = (const float*)d_in[14];
    const float* w31 = (const float*)d_in[15]; const float* b31 = (const float*)d_in[16];
    const float* w32 = (const float*)d_in[17]; const float* b32 = (const float*)d_in[18];
    const float* lw1 = (const float*)d_in[19]; const float* lb1 = (const float*)d_in[20];
    const float* lw2 = (const float*)d_in[21]; const float* lb2 = (const float*)d_in[22];
    const float* fw1 = (const float*)d_in[23]; const float* fb1 = (const float*)d_in[24];
    const float* fw2 = (const float*)d_in[25]; const float* fb2 = (const float*)d_in[26];
    const float* pm  = (const float*)d_in[27]; const float* ps  = (const float*)d_in[28];
    const float* rm  = (const float*)d_in[29]; const float* rs  = (const float*)d_in[30];
    float* out = (float*)d_out;

    char* p = (char*)d_ws;
    float* l1x  = (float*)p; p += align256((size_t)BB * 512 * 3 * 4);
    int*   idx1 = (int*)p;   p += align256((size_t)BB * 512 * 32 * 4);
    float* l1f  = (float*)p; p += align256((size_t)BB * 512 * 128 * 4);
    float* l2x  = (float*)p; p += align256((size_t)BB * 128 * 3 * 4);
    int*   idx2 = (int*)p;   p += align256((size_t)BB * 128 * 64 * 4);
    float* x3t  = (float*)p; p += align256((size_t)259 * 2048 * 4);
    float* h1t  = (float*)p; p += align256((size_t)256 * 2048 * 4);
    float* h2t  = (float*)p; p += align256((size_t)512 * 2048 * 4);
    float* g    = (float*)p; p += align256((size_t)BB * 1024 * 4);

    const float R2A = (float)(0.2 * 0.2);
    const float R2B = (float)(0.4 * 0.4);

    fps_kernel<4096, 512, 256><<<BB, 256, 0, stream>>>(points, l1x, (float*)nullptr, 0);
    ballquery_kernel<32><<<2048, 256, 0, stream>>>(points, 4096, l1x, 512, R2A, idx1);
    sa1_kernel<<<4096, 64, 0, stream>>>(points, l1x, idx1, w10, b10, w11, b11, w12, b12, l1f);
    fps_kernel<512, 128, 256><<<BB, 256, 0, stream>>>(l1x, l2x, x3t, 2048);
    ballquery_kernel<64><<<512, 256, 0, stream>>>(l1x, 512, l2x, 128, R2B, idx2);
    sa2_kernel<<<2048, 256, 0, stream>>>(l1x, l2x, l1f, idx2, w20, b20, w21, b21, w22, b22, x3t);
    zerog_kernel<<<BB, 1024, 0, stream>>>(g);
    gemm_t_kernel<259, 256, 16, false><<<512, 64, 0, stream>>>(x3t, w30, b30, h1t);
    gemm_t_kernel<256, 512, 16, false><<<1024, 64, 0, stream>>>(h1t, w31, b31, h2t);
    gemm_t_kernel<512, 1024, 16, true><<<2048, 64, 0, stream>>>(h2t, w32, b32, g);
    head_kernel<<<BB, 512, 0, stream>>>(g, lw1, lb1, lw2, lb2, fw1, fb1, fw2, fb2, pm, ps, rm, rs, out);
}

// Round 8
// 1029.397 us; speedup vs baseline: 1.2473x; 1.2473x over previous
//
#include <hip/hip_runtime.h>
#include <math.h>

#define BB 16
#define NN 4096

__device__ __forceinline__ float sq3(float dx, float dy, float dz) {
    // match numpy: ((dx*dx + dy*dy) + dz*dz), no fma contraction
    return __fadd_rn(__fadd_rn(__fmul_rn(dx, dx), __fmul_rn(dy, dy)), __fmul_rn(dz, dz));
}

// One DPP max step on a packed u64 (non-negative): o = dpp(P); P = max(P,o).
// bound_ctrl=1 -> invalid lanes read 0; 0 is identity for our u64 max.
template<int CTRL, int RMASK>
__device__ __forceinline__ unsigned long long dpp_max_step(unsigned long long P) {
    int lo = __builtin_amdgcn_update_dpp(0, (int)(unsigned)P,        CTRL, RMASK, 0xf, true);
    int hi = __builtin_amdgcn_update_dpp(0, (int)(unsigned)(P >> 32), CTRL, RMASK, 0xf, true);
    unsigned long long o = ((unsigned long long)(unsigned)hi << 32) | (unsigned)lo;
    return (o > P) ? o : P;
}

// Full-wave u64 max via DPP (VALU-latency, no LDS shuffles). Result valid in lane 63.
__device__ __forceinline__ unsigned long long dpp_wave_max_u64(unsigned long long P) {
    P = dpp_max_step<0x111, 0xf>(P);   // row_shr:1
    P = dpp_max_step<0x112, 0xf>(P);   // row_shr:2
    P = dpp_max_step<0x114, 0xf>(P);   // row_shr:4
    P = dpp_max_step<0x118, 0xf>(P);   // row_shr:8
    P = dpp_max_step<0x142, 0xa>(P);   // row_bcast15
    P = dpp_max_step<0x143, 0xc>(P);   // row_bcast31 -> lane 63 has wave max
    return P;
}

__device__ __forceinline__ unsigned long long u64max(unsigned long long a, unsigned long long b) {
    return (a > b) ? a : b;
}

// ---------------- FPS (one block per batch, sequential argmax) ----------------
// r6 config (best known: 307us): TPB=512 (2 waves/SIMD overlap!), u64-only DPP
// reduce, coords staged in LDS, myfar latch + single final write, one barrier
// per iteration (double-buffered slots). Tree compare on the 8 slots.
template<int NPTS, int NPOINT, int TPB>
__global__ __launch_bounds__(TPB) void fps_kernel(const float* __restrict__ xyz,   // [B][NPTS][3]
                                                  float* __restrict__ newxyz,      // [B][NPOINT][3]
                                                  float* __restrict__ out_t,       // optional transposed rows 0..2, stride ts
                                                  int ts) {
    constexpr int PPT = NPTS / TPB;
    constexpr int NW  = TPB / 64;
    static_assert(NPOINT <= TPB, "far-history latch needs NPOINT <= TPB");
    __shared__ float sx[NPTS], sy[NPTS], sz[NPTS];
    __shared__ __align__(16) unsigned long long slot[2][NW];
    const int b = blockIdx.x;
    const int tid = threadIdx.x;
    const float* base = xyz + (size_t)b * NPTS * 3;
    for (int i = tid; i < NPTS; i += TPB) {
        sx[i] = base[i * 3 + 0];
        sy[i] = base[i * 3 + 1];
        sz[i] = base[i * 3 + 2];
    }
    __syncthreads();
    float px[PPT], py[PPT], pz[PPT], dist[PPT];
#pragma unroll
    for (int k = 0; k < PPT; k++) {
        int p = tid + k * TPB;
        px[k] = sx[p]; py[k] = sy[p]; pz[k] = sz[p];
        dist[k] = 1e10f;
    }
    int far = 0;
    int myfar = 0;
    const int lane = tid & 63, wid = tid >> 6;
    for (int it = 0; it < NPOINT; it++) {
        if (tid == it) myfar = far;          // latch entering-far for the final write
        float fx = sx[far], fy = sy[far], fz = sz[far];
        float bv = -1.0f; int bi = 0;
#pragma unroll
        for (int k = 0; k < PPT; k++) {
            float d = sq3(px[k] - fx, py[k] - fy, pz[k] - fz);
            float nd = fminf(dist[k], d);
            dist[k] = nd;
            if (nd > bv) { bv = nd; bi = tid + k * TPB; }   // strict > keeps smallest k
        }
        unsigned long long P = ((unsigned long long)__float_as_uint(bv) << 32)
                             | (unsigned long long)(~(unsigned)bi & 0xFFFFFFFFull);
        P = dpp_wave_max_u64(P);
        int bufi = it & 1;
        if (lane == 63) slot[bufi][wid] = P;
        __syncthreads();
        unsigned long long best;
        if (NW == 8) {   // tree: depth 3 instead of 7-deep chain
            unsigned long long m01 = u64max(slot[bufi][0], slot[bufi][1]);
            unsigned long long m23 = u64max(slot[bufi][2], slot[bufi][3]);
            unsigned long long m45 = u64max(slot[bufi][4], slot[bufi][5]);
            unsigned long long m67 = u64max(slot[bufi][6], slot[bufi][7]);
            best = u64max(u64max(m01, m23), u64max(m45, m67));
        } else {
            best = slot[bufi][0];
#pragma unroll
            for (int w = 1; w < NW; w++) best = u64max(best, slot[bufi][w]);
        }
        far = (int)(~(unsigned)(best & 0xFFFFFFFFull));
    }
    if (tid < NPOINT) {
        float fx = sx[myfar], fy = sy[myfar], fz = sz[myfar];
        newxyz[((size_t)b * NPOINT + tid) * 3 + 0] = fx;
        newxyz[((size_t)b * NPOINT + tid) * 3 + 1] = fy;
        newxyz[((size_t)b * NPOINT + tid) * 3 + 2] = fz;
        if (out_t) {
            out_t[0 * ts + b * NPOINT + tid] = fx;
            out_t[1 * ts + b * NPOINT + tid] = fy;
            out_t[2 * ts + b * NPOINT + tid] = fz;
        }
    }
}

// ---------------- ball query body: one wave per center, ballot rounds ----------------
template<int NS>
__device__ __forceinline__ void bq_body(const float* __restrict__ pts, int n,
                                        const float* __restrict__ centers, int S,
                                        float r2, int* __restrict__ outidx,
                                        int wave, int lane) {
    int b = wave / S, s = wave % S;
    const float* c = centers + ((size_t)b * S + s) * 3;
    float cx = c[0], cy = c[1], cz = c[2];
    const float* pb = pts + (size_t)b * n * 3;
    int* out = outidx + ((size_t)b * S + s) * NS;
    int total = 0, first = -1;
    int rounds = n >> 6;
    for (int r = 0; r < rounds; r++) {
        int p = (r << 6) + lane;
        float dx = pb[p * 3 + 0] - cx, dy = pb[p * 3 + 1] - cy, dz = pb[p * 3 + 2] - cz;
        float d = sq3(dx, dy, dz);
        bool pred = (d <= r2);
        unsigned long long mask = __ballot(pred);
        if (first < 0 && mask) first = (r << 6) + (__ffsll(mask) - 1);
        if (pred) {
            int rank = total + __popcll(mask & ((1ull << lane) - 1ull));
            if (rank < NS) out[rank] = p;
        }
        total += __popcll(mask);
        if (total >= NS) break;
    }
    for (int j = total + lane; j < NS; j += 64) out[j] = first;
}

// ---------------- fused: fps2 (blocks 0..15) + ballquery1 (blocks 16..1039) ----------------
// Both depend only on l1x (fps1 output); outputs are independent. fps2 blocks
// first so the serial FPS starts immediately and hides under bq1's ~8192 waves.
__global__ __launch_bounds__(512) void bq1_fps2_kernel(const float* __restrict__ points,
                                                       const float* __restrict__ l1x,
                                                       float* __restrict__ l2x,
                                                       float* __restrict__ x3t,
                                                       int* __restrict__ idx1,
                                                       float r2a) {
    __shared__ float sx[512], sy[512], sz[512];
    __shared__ __align__(16) unsigned long long slot[2][8];
    const int tid = threadIdx.x;
    const int lane = tid & 63, wid = tid >> 6;
    if (blockIdx.x < 16) {
        // ---- FPS over l1x: 512 pts -> 128, PPT=1 ----
        const int b = blockIdx.x;
        const float* base = l1x + (size_t)b * 512 * 3;
        sx[tid] = base[tid * 3 + 0];
        sy[tid] = base[tid * 3 + 1];
        sz[tid] = base[tid * 3 + 2];
        __syncthreads();
        float px = sx[tid], py = sy[tid], pz = sz[tid], dist = 1e10f;
        int far = 0, myfar = 0;
        for (int it = 0; it < 128; it++) {
            if (tid == it) myfar = far;
            float fx = sx[far], fy = sy[far], fz = sz[far];
            float d = sq3(px - fx, py - fy, pz - fz);
            float nd = fminf(dist, d);
            dist = nd;
            unsigned long long P = ((unsigned long long)__float_as_uint(nd) << 32)
                                 | (unsigned long long)(~(unsigned)tid & 0xFFFFFFFFull);
            P = dpp_wave_max_u64(P);
            int bufi = it & 1;
            if (lane == 63) slot[bufi][wid] = P;
            __syncthreads();
            unsigned long long m01 = u64max(slot[bufi][0], slot[bufi][1]);
            unsigned long long m23 = u64max(slot[bufi][2], slot[bufi][3]);
            unsigned long long m45 = u64max(slot[bufi][4], slot[bufi][5]);
            unsigned long long m67 = u64max(slot[bufi][6], slot[bufi][7]);
            unsigned long long best = u64max(u64max(m01, m23), u64max(m45, m67));
            far = (int)(~(unsigned)(best & 0xFFFFFFFFull));
        }
        if (tid < 128) {
            float fx = sx[myfar], fy = sy[myfar], fz = sz[myfar];
            l2x[((size_t)b * 128 + tid) * 3 + 0] = fx;
            l2x[((size_t)b * 128 + tid) * 3 + 1] = fy;
            l2x[((size_t)b * 128 + tid) * 3 + 2] = fz;
            x3t[0 * 2048 + b * 128 + tid] = fx;
            x3t[1 * 2048 + b * 128 + tid] = fy;
            x3t[2 * 2048 + b * 128 + tid] = fz;
        }
    } else {
        int wave = (blockIdx.x - 16) * 8 + wid;   // 1024 blocks x 8 waves = 8192 = 16*512
        bq_body<32>(points, 4096, l1x, 512, r2a, idx1, wave, lane);
    }
}

// ---------------- fused: ballquery2 (blocks 0..2047) + SA1 (blocks 2048..6143) ----------------
// bq2 needs l2x, sa1 needs idx1 — both ready after bq1_fps2; outputs independent.
__global__ __launch_bounds__(64, 2) void sa1_bq2_kernel(const float* __restrict__ xyz, const float* __restrict__ l1x,
                                                 const int* __restrict__ idx1,
                                                 const float* __restrict__ l2x, int* __restrict__ idx2, float r2b,
                                                 const float* __restrict__ W1, const float* __restrict__ B1,
                                                 const float* __restrict__ W2, const float* __restrict__ B2,
                                                 const float* __restrict__ W3, const float* __restrict__ B3,
                                                 float* __restrict__ l1f) {
    __shared__ float ht[64 * 64];
    int lane = threadIdx.x;
    if (blockIdx.x < 2048) {
        bq_body<64>(l1x, 512, l2x, 128, r2b, idx2, blockIdx.x, lane);
        return;
    }
    int blk = blockIdx.x - 2048;
    int b = blk >> 8;
    int s = ((blk & 255) << 1) | (lane >> 5);
    int nn = lane & 31;
    int center = b * 512 + s;
    int ii = idx1[center * 32 + nn];
    float px = xyz[((size_t)b * NN + ii) * 3 + 0] - l1x[(size_t)center * 3 + 0];
    float py = xyz[((size_t)b * NN + ii) * 3 + 1] - l1x[(size_t)center * 3 + 1];
    float pz = xyz[((size_t)b * NN + ii) * 3 + 2] - l1x[(size_t)center * 3 + 2];
#pragma unroll
    for (int c = 0; c < 64; c++)
        ht[c * 64 + lane] = fmaxf(B1[c] + px * W1[c] + py * W1[64 + c] + pz * W1[128 + c], 0.0f);
    __syncthreads();
    float h2[64];
#pragma unroll
    for (int c = 0; c < 64; c++) h2[c] = B2[c];
    for (int k = 0; k < 64; k++) {
        float xk = ht[k * 64 + lane];
        const float* wr = W2 + k * 64;
#pragma unroll
        for (int c = 0; c < 64; c++) h2[c] += xk * wr[c];
    }
    __syncthreads();
#pragma unroll
    for (int c = 0; c < 64; c++) ht[c * 64 + lane] = fmaxf(h2[c], 0.0f);
    __syncthreads();
#pragma unroll
    for (int half = 0; half < 2; half++) {
        float o[64];
#pragma unroll
        for (int j = 0; j < 64; j++) o[j] = B3[half * 64 + j];
        for (int k = 0; k < 64; k++) {
            float xk = ht[k * 64 + lane];
            const float* wr = W3 + k * 128 + half * 64;
#pragma unroll
            for (int j = 0; j < 64; j++) o[j] += xk * wr[j];
        }
#pragma unroll
        for (int j = 0; j < 64; j++) {
            float v = fmaxf(o[j], 0.0f);
#pragma unroll
            for (int m = 16; m >= 1; m >>= 1) v = fmaxf(v, __shfl_xor(v, m));
            o[j] = v;
        }
        if (nn == 0) {
#pragma unroll
            for (int j = 0; j < 64; j++) l1f[(size_t)center * 128 + half * 64 + j] = o[j];
        }
    }
}

// ---------------- SA2 MLP: 131->128->128->256, max over 64 nbrs ----------------
// 256 threads = 4 waves x 32 channels (r5 fix: occupancy/s_load pipelining).
__global__ __launch_bounds__(256, 2) void sa2_kernel(const float* __restrict__ l1x, const float* __restrict__ l2x,
                                                  const float* __restrict__ l1f, const int* __restrict__ idx2,
                                                  const float* __restrict__ W1, const float* __restrict__ B1,
                                                  const float* __restrict__ W2, const float* __restrict__ B2,
                                                  const float* __restrict__ W3, const float* __restrict__ B3,
                                                  float* __restrict__ x3t) {
    __shared__ float ht[128 * 64];
    int tid = threadIdx.x;
    int w = __builtin_amdgcn_readfirstlane(tid >> 6);   // 0..3, wave-uniform -> SGPR
    int lane = tid & 63;
    int b = blockIdx.x >> 7, s = blockIdx.x & 127;
    int center = b * 128 + s;
    int ii = idx2[center * 64 + lane];
    float cx = l2x[(size_t)center * 3 + 0], cy = l2x[(size_t)center * 3 + 1], cz = l2x[(size_t)center * 3 + 2];
    const float* pr = l1x + ((size_t)b * 512 + ii) * 3;
    float px = pr[0] - cx, py = pr[1] - cy, pz = pr[2] - cz;
    const float4* frow = (const float4*)(l1f + ((size_t)b * 512 + ii) * 128);
    float h[32];
#pragma unroll
    for (int j = 0; j < 32; j++) {
        int c = w * 32 + j;
        h[j] = B1[c] + px * W1[c] + py * W1[128 + c] + pz * W1[256 + c];
    }
    for (int k4 = 0; k4 < 32; k4++) {
        float4 f = frow[k4];
        const float* wr = W1 + (3 + k4 * 4) * 128 + w * 32;
#pragma unroll
        for (int j = 0; j < 32; j++)
            h[j] += f.x * wr[j] + f.y * wr[128 + j] + f.z * wr[256 + j] + f.w * wr[384 + j];
    }
#pragma unroll
    for (int j = 0; j < 32; j++) ht[(w * 32 + j) * 64 + lane] = fmaxf(h[j], 0.0f);
    __syncthreads();
    float h2[32];
#pragma unroll
    for (int j = 0; j < 32; j++) h2[j] = B2[w * 32 + j];
    for (int k = 0; k < 128; k++) {
        float xk = ht[k * 64 + lane];
        const float* wr = W2 + k * 128 + w * 32;
#pragma unroll
        for (int j = 0; j < 32; j++) h2[j] += xk * wr[j];
    }
    __syncthreads();
#pragma unroll
    for (int j = 0; j < 32; j++) ht[(w * 32 + j) * 64 + lane] = fmaxf(h2[j], 0.0f);
    __syncthreads();
#pragma unroll
    for (int half = 0; half < 2; half++) {
        float o[32];
#pragma unroll
        for (int j = 0; j < 32; j++) o[j] = B3[w * 64 + half * 32 + j];
        for (int k = 0; k < 128; k++) {
            float xk = ht[k * 64 + lane];
            const float* wr = W3 + k * 256 + w * 64 + half * 32;
#pragma unroll
            for (int j = 0; j < 32; j++) o[j] += xk * wr[j];
        }
#pragma unroll
        for (int j = 0; j < 32; j++) {
            float v = fmaxf(o[j], 0.0f);
#pragma unroll
            for (int m = 32; m >= 1; m >>= 1) v = fmaxf(v, __shfl_xor(v, m));
            o[j] = v;
        }
        if (lane == 0) {
#pragma unroll
            for (int j = 0; j < 32; j++)
                x3t[(size_t)(3 + w * 64 + half * 32 + j) * 2048 + center] = o[j];
        }
    }
}

// ---------------- transposed GEMM body for SA3 ----------------
template<int K, int COUT, int CPT, bool MAXOUT>
__device__ __forceinline__ void gemm_t_body(const float* __restrict__ in_t,
                                            const float* __restrict__ W,
                                            const float* __restrict__ bias,
                                            float* __restrict__ outp,
                                            int bid, int lane) {
    int rw = bid & 31, cg = bid >> 5;
    int row = rw * 64 + lane;
    int cbase = cg * CPT;
    float acc[CPT];
#pragma unroll
    for (int j = 0; j < CPT; j++) acc[j] = bias[cbase + j];
    for (int k = 0; k < K; k++) {
        float xk = in_t[(size_t)k * 2048 + row];
        const float* wr = W + (size_t)k * COUT + cbase;
#pragma unroll
        for (int j = 0; j < CPT; j++) acc[j] += xk * wr[j];
    }
    if (MAXOUT) {
        int b = row >> 7;
#pragma unroll
        for (int j = 0; j < CPT; j++) {
            float v = fmaxf(acc[j], 0.0f);
#pragma unroll
            for (int m = 32; m >= 1; m >>= 1) v = fmaxf(v, __shfl_xor(v, m));
            if (lane == 0)
                atomicMax((int*)(outp + (size_t)b * 1024 + cbase + j), __float_as_int(v));
        }
    } else {
#pragma unroll
        for (int j = 0; j < CPT; j++)
            outp[(size_t)(cbase + j) * 2048 + row] = fmaxf(acc[j], 0.0f);
    }
}

template<int K, int COUT, int CPT, bool MAXOUT>
__global__ __launch_bounds__(64, 4) void gemm_t_kernel(const float* __restrict__ in_t,
                                                    const float* __restrict__ W,
                                                    const float* __restrict__ bias,
                                                    float* __restrict__ outp) {
    gemm_t_body<K, COUT, CPT, MAXOUT>(in_t, W, bias, outp, blockIdx.x, threadIdx.x);
}

// gemm1 (blocks 0..511) + zero-init of g (blocks 512..767; g untouched until gemm3)
__global__ __launch_bounds__(64, 4) void gemm1_zerog_kernel(const float* __restrict__ in_t,
                                                            const float* __restrict__ W,
                                                            const float* __restrict__ bias,
                                                            float* __restrict__ outp,
                                                            float* __restrict__ g) {
    if (blockIdx.x < 512) {
        gemm_t_body<259, 256, 16, false>(in_t, W, bias, outp, blockIdx.x, threadIdx.x);
    } else {
        g[(blockIdx.x - 512) * 64 + threadIdx.x] = 0.0f;
    }
}

// ---------------- FC heads ----------------
__global__ __launch_bounds__(512) void head_kernel(const float* __restrict__ g,
                                                   const float* __restrict__ lw1, const float* __restrict__ lb1,
                                                   const float* __restrict__ lw2, const float* __restrict__ lb2,
                                                   const float* __restrict__ fw1, const float* __restrict__ fb1,
                                                   const float* __restrict__ fw2, const float* __restrict__ fb2,
                                                   const float* __restrict__ pm, const float* __restrict__ ps,
                                                   const float* __restrict__ rm, const float* __restrict__ rs,
                                                   float* __restrict__ out) {
    __shared__ float gl[1024], a1[256], f1[512];
    int b = blockIdx.x, t = threadIdx.x;
    for (int i = t; i < 1024; i += 512) gl[i] = g[b * 1024 + i];
    __syncthreads();
    {
        float acc = fb1[t];
        for (int k = 0; k < 1024; k++) acc += gl[k] * fw1[k * 512 + t];
        f1[t] = fmaxf(acc, 0.0f);
    }
    if (t < 256) {
        float acc = lb1[t];
        for (int k = 0; k < 1024; k++) acc += gl[k] * lw1[k * 256 + t];
        a1[t] = fmaxf(acc, 0.0f);
    }
    __syncthreads();
    if (t < 2) {
        float z = lb2[t];
        for (int k = 0; k < 256; k++) z += a1[k] * lw2[k * 2 + t];
        out[b * 20 + t] = 1.0f / (1.0f + expf(-z));
    } else if (t < 20) {
        int i = t - 2;
        float z = fb2[i];
        for (int k = 0; k < 512; k++) z += f1[k] * fw2[k * 18 + i];
        float sc, mn;
        if (i < 3)       { sc = ps[i];      mn = pm[i]; }
        else if (i < 9)  { sc = rs[i - 3];  mn = rm[i - 3]; }
        else if (i < 12) { sc = ps[i - 9];  mn = pm[i - 9]; }
        else             { sc = rs[i - 12]; mn = rm[i - 12]; }
        out[b * 20 + t] = z * sc + mn;
    }
}

static inline size_t align256(size_t x) { return (x + 255) & ~(size_t)255; }

extern "C" void kernel_launch(void* const* d_in, const int* in_sizes, int n_in,
                              void* d_out, int out_size, void* d_ws, size_t ws_size,
                              hipStream_t stream) {
    const float* points = (const float*)d_in[0];
    const float* w10 = (const float*)d_in[1];  const float* b10 = (const float*)d_in[2];
    const float* w11 = (const float*)d_in[3];  const float* b11 = (const float*)d_in[4];
    const float* w12 = (const float*)d_in[5];  const float* b12 = (const float*)d_in[6];
    const float* w20 = (const float*)d_in[7];  const float* b20 = (const float*)d_in[8];
    const float* w21 = (const float*)d_in[9];  const float* b21 = (const float*)d_in[10];
    const float* w22 = (const float*)d_in[11]; const float* b22 = (const float*)d_in[12];
    const float* w30 = (const float*)d_in[13]; const float* b30 = (const float*)d_in[14];
    const float* w31 = (const float*)d_in[15]; const float* b31 = (const float*)d_in[16];
    const float* w32 = (const float*)d_in[17]; const float* b32 = (const float*)d_in[18];
    const float* lw1 = (const float*)d_in[19]; const float* lb1 = (const float*)d_in[20];
    const float* lw2 = (const float*)d_in[21]; const float* lb2 = (const float*)d_in[22];
    const float* fw1 = (const float*)d_in[23]; const float* fb1 = (const float*)d_in[24];
    const float* fw2 = (const float*)d_in[25]; const float* fb2 = (const float*)d_in[26];
    const float* pm  = (const float*)d_in[27]; const float* ps  = (const float*)d_in[28];
    const float* rm  = (const float*)d_in[29]; const float* rs  = (const float*)d_in[30];
    float* out = (float*)d_out;

    char* p = (char*)d_ws;
    float* l1x  = (float*)p; p += align256((size_t)BB * 512 * 3 * 4);
    int*   idx1 = (int*)p;   p += align256((size_t)BB * 512 * 32 * 4);
    float* l1f  = (float*)p; p += align256((size_t)BB * 512 * 128 * 4);
    float* l2x  = (float*)p; p += align256((size_t)BB * 128 * 3 * 4);
    int*   idx2 = (int*)p;   p += align256((size_t)BB * 128 * 64 * 4);
    float* x3t  = (float*)p; p += align256((size_t)259 * 2048 * 4);
    float* h1t  = (float*)p; p += align256((size_t)256 * 2048 * 4);
    float* h2t  = (float*)p; p += align256((size_t)512 * 2048 * 4);
    float* g    = (float*)p; p += align256((size_t)BB * 1024 * 4);

    const float R2A = (float)(0.2 * 0.2);
    const float R2B = (float)(0.4 * 0.4);

    fps_kernel<4096, 512, 512><<<BB, 512, 0, stream>>>(points, l1x, (float*)nullptr, 0);
    bq1_fps2_kernel<<<1040, 512, 0, stream>>>(points, l1x, l2x, x3t, idx1, R2A);
    sa1_bq2_kernel<<<6144, 64, 0, stream>>>(points, l1x, idx1, l2x, idx2, R2B,
                                            w10, b10, w11, b11, w12, b12, l1f);
    sa2_kernel<<<2048, 256, 0, stream>>>(l1x, l2x, l1f, idx2, w20, b20, w21, b21, w22, b22, x3t);
    gemm1_zerog_kernel<<<768, 64, 0, stream>>>(x3t, w30, b30, h1t, g);
    gemm_t_kernel<256, 512, 16, false><<<1024, 64, 0, stream>>>(h1t, w31, b31, h2t);
    gemm_t_kernel<512, 1024, 16, true><<<2048, 64, 0, stream>>>(h2t, w32, b32, g);
    head_kernel<<<BB, 512, 0, stream>>>(g, lw1, lb1, lw2, lb2, fw1, fb1, fw2, fb2, pm, ps, rm, rs, out);
}